// Round 16
// baseline (23.949 us; speedup 1.0000x reference)
//
#include <hip/hip_runtime.h>

#define N 512
#define SLICE (512 * 512)
#define KAPPA2 0.1089f   // 0.33^2
#define GAMMA  1.0f
#define BETA   25.0f

#define LDS_ROWS   6
#define BUF_FLOATS (LDS_ROWS * N)    // 3072 floats = 12 KB per buffer

typedef const __attribute__((address_space(1))) void gas_void;
typedef __attribute__((address_space(3))) void las_void;

// Async global->LDS DMA: wave-uniform LDS base, HW adds lane*16B.
// Per-lane global src must be base + lane*16B for a contiguous 1KB chunk.
__device__ __forceinline__ void gload_lds16(const float* g, float* l) {
    __builtin_amdgcn_global_load_lds((gas_void*)g, (las_void*)l, 16, 0, 0);
}

// Wave = full row: lane L owns px [8L, 8L+8). Span s[0..9] covers [8L-1, 8L+8].
__device__ __forceinline__ void span_from(const float4& A, const float4& B, int lane,
                                          float s[10]) {
    s[1] = A.x; s[2] = A.y; s[3] = A.z; s[4] = A.w;
    s[5] = B.x; s[6] = B.y; s[7] = B.z; s[8] = B.w;
    const float lw = __shfl_up(B.w, 1, 64);
    const float rx = __shfl_down(A.x, 1, 64);
    s[0] = (lane == 0)  ? 0.0f : lw;
    s[9] = (lane == 63) ? 0.0f : rx;
}

// state: [B=8, 9, 512, 512] f32. slices 0..6 = x_t, 7 = vx, 8 = vy.
// q per slice t: t=0: |Ax0|^2+1.05|x0|^2; t=1..5: |Mx|^2-2x_{t-1}.Mx+|x|^2;
// t=6: |Mx|^2-2x_5.Mx.  val = m*c + Ax; q += val^2 - 2*xp*val + ccoef*c^2;
// xp = previous t's center (registers).
// Stage 1: block = 4 waves = rows y0..y0+3 of one batch; per slice, 6 rows
// (y0-1..y0+4) staged ONCE into LDS (1.5x traffic vs 3x for per-wave loads),
// double-buffered: stage slice t+1 (async DMA) while computing slice t.
// bid = strip*8 + b: %8 round-robin pins batch->XCD.
__global__ __launch_bounds__(256, 4) void phi_q_stage1(const float* __restrict__ state,
                                                       float* __restrict__ ws) {
    __shared__ float lds[2 * BUF_FLOATS];   // 24 KB

    const int bid   = blockIdx.x;           // 1024 = 128 strips * 8 batches
    const int b     = bid & 7;
    const int strip = bid >> 3;
    const int y0    = strip * 4;
    const int tid   = threadIdx.x;
    const int w     = tid >> 6;              // wave -> row y0+w
    const int lane  = tid & 63;
    const int xo    = lane * 8;

    const float* base = state + (size_t)b * 9 * SLICE;
    const int    y    = y0 + w;
    const size_t ro   = (size_t)y * N + xo;

    // Grid-edge LDS rows are never staged: zero them once (both buffers).
    if (y0 == 0) {
        for (int i = tid; i < N; i += 256) {
            lds[i] = 0.0f; lds[BUF_FLOATS + i] = 0.0f;
        }
    }
    if (y0 == N - 4) {
        for (int i = tid; i < N; i += 256) {
            lds[5 * N + i] = 0.0f; lds[BUF_FLOATS + 5 * N + i] = 0.0f;
        }
    }

    // Diffusion tensor for this wave's row: loaded once, reused for all 7 t.
    float H11[8], H12[8], H22[8];
    {
        const float4 vxA = *reinterpret_cast<const float4*>(base + 7 * SLICE + ro);
        const float4 vxB = *reinterpret_cast<const float4*>(base + 7 * SLICE + ro + 4);
        const float4 vyA = *reinterpret_cast<const float4*>(base + 8 * SLICE + ro);
        const float4 vyB = *reinterpret_cast<const float4*>(base + 8 * SLICE + ro + 4);
        const float vxs[8] = {vxA.x, vxA.y, vxA.z, vxA.w, vxB.x, vxB.y, vxB.z, vxB.w};
        const float vys[8] = {vyA.x, vyA.y, vyA.z, vyA.w, vyB.x, vyB.y, vyB.z, vyB.w};
        #pragma unroll
        for (int j = 0; j < 8; ++j) {
            H11[j] = GAMMA + BETA * vxs[j] * vxs[j];
            H12[j] = 2.0f * BETA * vxs[j] * vys[j];
            H22[j] = GAMMA + BETA * vys[j] * vys[j];
        }
    }

    // Stage slice t into LDS buffer at byte-offset bufoff: 12 chunks of 1 KB
    // (6 rows x 2); wave w issues chunks k = 3w .. 3w+2 (r = k>>1, half = k&1).
    auto stage = [&](int t, int bufoff) {
        const float* u = base + (size_t)t * SLICE;
        #pragma unroll
        for (int k3 = 0; k3 < 3; ++k3) {
            const int k  = w * 3 + k3;
            const int r  = k >> 1;
            const int c  = (k & 1) * 256;
            const int gy = y0 - 1 + r;
            if (gy >= 0 && gy < N) {      // wave-uniform
                gload_lds16(u + (size_t)gy * N + c + lane * 4,
                            &lds[bufoff + r * N + c]);
            }
        }
    };

    stage(0, 0);
    asm volatile("s_waitcnt vmcnt(0)" ::: "memory");
    __syncthreads();

    float xprev[8];
    #pragma unroll
    for (int j = 0; j < 8; ++j) xprev[j] = 0.0f;

    float q = 0.0f;
    float m = 0.0f;               // 0 at t=0 (val=Ax), 1 after (val=Mx)

    #pragma unroll 1
    for (int t = 0; t < 7; ++t) {
        const int cur = (t & 1) * BUF_FLOATS;
        if (t < 6) stage(t + 1, BUF_FLOATS - cur);

        // Rows w, w+1, w+2 of the current buffer = global rows y-1, y, y+1.
        const float4 mA = *reinterpret_cast<const float4*>(&lds[cur + (w + 0) * N + xo]);
        const float4 mB = *reinterpret_cast<const float4*>(&lds[cur + (w + 0) * N + xo + 4]);
        const float4 cA = *reinterpret_cast<const float4*>(&lds[cur + (w + 1) * N + xo]);
        const float4 cB = *reinterpret_cast<const float4*>(&lds[cur + (w + 1) * N + xo + 4]);
        const float4 uA = *reinterpret_cast<const float4*>(&lds[cur + (w + 2) * N + xo]);
        const float4 uB = *reinterpret_cast<const float4*>(&lds[cur + (w + 2) * N + xo + 4]);

        float sm[10], sc[10], su[10];
        span_from(cA, cB, lane, sc);
        span_from(mA, mB, lane, sm);
        span_from(uA, uB, lane, su);

        const float ccoef = (t == 0) ? 1.05f : ((t < 6) ? 1.0f : 0.0f);

        #pragma unroll
        for (int j = 0; j < 8; ++j) {
            const float c   = sc[j + 1];
            const float uxx = sc[j] + sc[j + 2] - 2.0f * c;
            const float uyy = sm[j + 1] + su[j + 1] - 2.0f * c;
            const float uxy = 0.25f * (su[j + 2] - su[j] - sm[j + 2] + sm[j]);
            const float div = H11[j] * uxx + H12[j] * uxy + H22[j] * uyy;
            const float Ax  = KAPPA2 * c - div;
            const float val = m * c + Ax;            // Ax at t=0, Mx else
            q += val * val - 2.0f * xprev[j] * val + ccoef * c * c;
            xprev[j] = c;                            // x_t for next iteration
        }
        m = 1.0f;

        // Drain the async stage of t+1, and fence buffer reuse, then swap.
        asm volatile("s_waitcnt vmcnt(0)" ::: "memory");
        __syncthreads();
    }

    // wave reduce + block reduce -> one partial per block
    #pragma unroll
    for (int off = 32; off > 0; off >>= 1)
        q += __shfl_down(q, off, 64);

    __shared__ float sred[4];
    if (lane == 0) sred[w] = q;
    __syncthreads();
    if (tid == 0) ws[bid] = sred[0] + sred[1] + sred[2] + sred[3];
}

// Stage 2: 8 blocks; block b sums its 128 partials (ws[b + 8k]).
__global__ __launch_bounds__(128) void phi_q_stage2(const float* __restrict__ ws,
                                                    float* __restrict__ out) {
    const int b = blockIdx.x;
    float v = ws[b + 8 * threadIdx.x];
    #pragma unroll
    for (int off = 32; off > 0; off >>= 1)
        v += __shfl_down(v, off, 64);

    __shared__ float sred[2];
    const int lane = threadIdx.x & 63;
    const int wid  = threadIdx.x >> 6;
    if (lane == 0) sred[wid] = v;
    __syncthreads();
    if (threadIdx.x == 0) out[b] = sred[0] + sred[1];
}

extern "C" void kernel_launch(void* const* d_in, const int* in_sizes, int n_in,
                              void* d_out, int out_size, void* d_ws, size_t ws_size,
                              hipStream_t stream) {
    const float* state = (const float*)d_in[0];
    float* out = (float*)d_out;
    float* ws  = (float*)d_ws;

    phi_q_stage1<<<1024, 256, 0, stream>>>(state, ws);
    phi_q_stage2<<<8, 128, 0, stream>>>(ws, out);
}